// Round 15
// baseline (614.241 us; speedup 1.0000x reference)
//
#include <hip/hip_runtime.h>
#include <float.h>
#include <math.h>

#define NGR 64        // graphs
#define NPG0 1000     // original nodes per graph
#define HDIM 128
#define EG 16000      // edges per graph
#define NE (NGR*EG)   // 1,024,000
#define RPS 1008      // rp row stride
#define BNEPS 1e-5f
#define POOL_NB 16

// ---------------- invnorm of pool_w rows (6 layers) ----------------
__global__ void k_invnorm(const float* __restrict__ pw, float* __restrict__ invnorm){
  int i = blockIdx.x;                  // layer
  int t = threadIdx.x;                 // 128 threads
  float v = pw[i*HDIM + t];
  float s = v*v;
  #pragma unroll
  for(int o=32;o>0;o>>=1) s += __shfl_down(s, o, 64);
  __shared__ float red[2];
  if((t & 63)==0) red[t>>6] = s;
  __syncthreads();
  if(t==0) invnorm[i] = 1.0f / sqrtf(red[0]+red[1]);
}

// ---------------- build phase: per-graph-chunk LDS count + weighted degree ----------------
__global__ __launch_bounds__(256) void k_count0(const int* __restrict__ dst,
    const float* __restrict__ we, int* __restrict__ pcnt, float* __restrict__ pdeg){
  int g = blockIdx.x >> 2, sub = blockIdx.x & 3, t = threadIdx.x;
  __shared__ int   cnt[NPG0];
  __shared__ float degl[NPG0];
  for(int i=t;i<NPG0;i+=256){ cnt[i]=0; degl[i]=0.f; }
  __syncthreads();
  int base = g*EG + sub*4000;
  for(int idx=t; idx<4000; idx+=256){
    int e = base + idx;
    int ld = dst[e] - g*NPG0;
    atomicAdd(&cnt[ld], 1);
    atomicAdd(&degl[ld], we[e]);
  }
  __syncthreads();
  int p = blockIdx.x * NPG0;
  for(int i=t;i<NPG0;i+=256){ pcnt[p+i] = cnt[i]; pdeg[p+i] = degl[i]; }
}

// ---------------- fused scan + scatter: block g owns graph g ----------------
// ec record = (float w)<<32 | src_orig (static for whole run).
__global__ __launch_bounds__(1024) void k_build(const int* __restrict__ pcnt,
    const float* __restrict__ pdeg, const int* __restrict__ src,
    const int* __restrict__ dst, const float* __restrict__ we,
    int* __restrict__ rp, float* __restrict__ dinvz, float* __restrict__ gsc,
    long long* __restrict__ ec){
  int g = blockIdx.x, t = threadIdx.x;
  __shared__ int sc[2][1024];
  __shared__ int cur[NPG0];
  int c = 0;
  if(t < NPG0){
    c = pcnt[(g*4+0)*NPG0+t] + pcnt[(g*4+1)*NPG0+t]
      + pcnt[(g*4+2)*NPG0+t] + pcnt[(g*4+3)*NPG0+t];
    float dg = pdeg[(g*4+0)*NPG0+t] + pdeg[(g*4+1)*NPG0+t]
             + pdeg[(g*4+2)*NPG0+t] + pdeg[(g*4+3)*NPG0+t];
    float dv = 1.0f / sqrtf(dg + 1.0f);
    dinvz[g*NPG0+t] = dv;
    gsc[g*NPG0+t]   = dv;        // layer-0 feature scale: val == 1
  }
  sc[0][t] = c;
  __syncthreads();
  int buf = 0;
  for(int d=1; d<1024; d<<=1){
    int v = sc[buf][t];
    if(t>=d) v += sc[buf][t-d];
    sc[buf^1][t] = v;
    __syncthreads();
    buf ^= 1;
  }
  if(t<=NPG0) rp[g*RPS+t] = (t==0) ? 0 : sc[buf][t-1];
  if(t<NPG0)  cur[t]      = (t==0) ? 0 : sc[buf][t-1];
  __syncthreads();
  int base = g*EG;
  for(int idx=t; idx<EG; idx+=1024){
    int e = base + idx;
    int ld = dst[e] - g*NPG0;
    int pos = atomicAdd(&cur[ld], 1);
    ec[(size_t)base + pos] = (((long long)__float_as_int(we[e]))<<32) | (unsigned)src[e];
  }
}

// ---------------- aggregation over original-id buckets ----------------
// agg[compact dst row] = dvd * ( sum_e w*gsc[src]*raw[src] + gsc[d]*raw[d] )
template<int L0>
__global__ __launch_bounds__(256) void k_agg(int n, const int* __restrict__ nlist,
    const int* __restrict__ rp, const long long* __restrict__ ec,
    const float* __restrict__ dinvz, const float* __restrict__ gsc,
    const float* __restrict__ h, float* __restrict__ agg){
  int g = blockIdx.x & 63;            // graph-major: XCD locality
  int chunk = blockIdx.x >> 6;
  int wid = threadIdx.x >> 6, lane = threadIdx.x & 63;
  const int wpg = (gridDim.x >> 6) * 4;
  const int half = lane >> 5, sl32 = lane & 31;   // 128-col split
  const int qw   = lane >> 4, sl16 = lane & 15;   // 64-col split
  for(int j = chunk*4 + wid; j < n; j += wpg){
    int cg = g*n + j;                               // compact row
    int d  = L0 ? (g*NPG0 + j) : nlist[cg];         // original id
    int ld = d - g*NPG0;
    int e0 = rp[g*RPS+ld], e1 = rp[g*RPS+ld+1];
    float dvd = dinvz[d];
    float gsd = gsc[d];
    float4 acc; acc.x=0.f; acc.y=0.f; acc.z=0.f; acc.w=0.f;
    for(int b=e0;b<e1;b+=64){
      int mm = e1-b; if(mm>64) mm=64;
      long long rec = (lane<mm) ? ec[(size_t)g*EG + b + lane] : 0;
      int   sl = (int)(rec & 0xffffffffLL);
      float cl = __int_as_float((int)(rec>>32)) * gsc[sl];
      long long pk = (((long long)__float_as_int(cl))<<32) | (unsigned)sl;
      if(L0){
        int mr = (mm+31) & ~31;
        for(int jj=0;jj<mr;jj+=32){
          #pragma unroll
          for(int u=0;u<8;u++){
            long long p = __shfl(pk, jj + 4*u + qw, 64);
            float c = __int_as_float((int)(p>>32));
            if(c != 0.f){
              int s = (int)(p & 0xffffffffLL);
              float4 hv = *(const float4*)(h + (size_t)s*64 + 4*sl16);
              acc.x += c*hv.x; acc.y += c*hv.y; acc.z += c*hv.z; acc.w += c*hv.w;
            }
          }
        }
      } else {
        int mr = (mm+15) & ~15;
        for(int jj=0;jj<mr;jj+=16){
          #pragma unroll
          for(int u=0;u<8;u++){
            long long p = __shfl(pk, jj + 2*u + half, 64);
            float c = __int_as_float((int)(p>>32));
            if(c != 0.f){
              int s = (int)(p & 0xffffffffLL);
              float4 hv = *(const float4*)(h + (size_t)s*HDIM + 4*sl32);
              acc.x += c*hv.x; acc.y += c*hv.y; acc.z += c*hv.z; acc.w += c*hv.w;
            }
          }
        }
      }
    }
    if(L0){
      acc.x += __shfl_xor(acc.x, 16, 64); acc.y += __shfl_xor(acc.y, 16, 64);
      acc.z += __shfl_xor(acc.z, 16, 64); acc.w += __shfl_xor(acc.w, 16, 64);
      acc.x += __shfl_xor(acc.x, 32, 64); acc.y += __shfl_xor(acc.y, 32, 64);
      acc.z += __shfl_xor(acc.z, 32, 64); acc.w += __shfl_xor(acc.w, 32, 64);
      if(qw==0){
        float4 hs = *(const float4*)(h + (size_t)d*64 + 4*sl16);
        float4 o;
        o.x = dvd*(acc.x + gsd*hs.x); o.y = dvd*(acc.y + gsd*hs.y);
        o.z = dvd*(acc.z + gsd*hs.z); o.w = dvd*(acc.w + gsd*hs.w);
        *(float4*)(agg + (size_t)cg*64 + 4*sl16) = o;
      }
    } else {
      acc.x += __shfl_xor(acc.x, 32, 64); acc.y += __shfl_xor(acc.y, 32, 64);
      acc.z += __shfl_xor(acc.z, 32, 64); acc.w += __shfl_xor(acc.w, 32, 64);
      if(half==0){
        float4 hs = *(const float4*)(h + (size_t)d*HDIM + 4*sl32);
        float4 o;
        o.x = dvd*(acc.x + gsd*hs.x); o.y = dvd*(acc.y + gsd*hs.y);
        o.z = dvd*(acc.z + gsd*hs.z); o.w = dvd*(acc.w + gsd*hs.w);
        *(float4*)(agg + (size_t)cg*HDIM + 4*sl32) = o;
      }
    }
  }
}

// ---------------- fp32 GEMM: A-tile fully LDS-resident, B streamed from global ----
// One barrier total (after A staging). B rows are wave-broadcast 512B reads that stay
// hot in L2 (W = 64KB/layer); loads pipeline across the unrolled k-loop with no
// barrier ever draining vmcnt. Output rows scattered to orig-id order.
template<int KIN>
__global__ __launch_bounds__(256) void k_gemm(const float* __restrict__ Ain,
    const float* __restrict__ Wm, const float* __restrict__ bias,
    const float* __restrict__ gamma, const float* __restrict__ beta,
    const float* __restrict__ mean, const float* __restrict__ var,
    const float* __restrict__ pw, const float* __restrict__ invn_p,
    const int* __restrict__ olist, float* __restrict__ hout, float* __restrict__ score){
  const int AS = KIN + 4;        // row stride, keeps rows 16B-aligned
  __shared__ float As[64*AS];    // 17.4KB (KIN=64) / 33.8KB (KIN=128)
  int t = threadIdx.x;
  int tx = t & 31, ty = t >> 5;  // thread: rows ty*8..+7, cols tx*4..+3
  int r0 = blockIdx.x * 64;
  // stage full 64xKIN A-tile via float4 (coalesced)
  #pragma unroll
  for(int p=0; p<(64*KIN/4)/256; p++){
    int idx = p*256 + t;
    int rr = idx/(KIN/4), kq = idx%(KIN/4);
    float4 av = *(const float4*)(Ain + (size_t)(r0+rr)*KIN + kq*4);
    *(float4*)&As[rr*AS + kq*4] = av;
  }
  __syncthreads();
  float acc[8][4];
  #pragma unroll
  for(int j=0;j<8;j++){
    #pragma unroll
    for(int i=0;i<4;i++) acc[j][i]=0.f;
  }
  #pragma unroll 2
  for(int kk=0;kk<KIN;kk+=4){
    float4 b0 = *(const float4*)(Wm + (size_t)(kk+0)*128 + tx*4);
    float4 b1 = *(const float4*)(Wm + (size_t)(kk+1)*128 + tx*4);
    float4 b2 = *(const float4*)(Wm + (size_t)(kk+2)*128 + tx*4);
    float4 b3 = *(const float4*)(Wm + (size_t)(kk+3)*128 + tx*4);
    #pragma unroll
    for(int j=0;j<8;j++){
      float4 a = *(float4*)&As[(ty*8+j)*AS + kk];
      acc[j][0] += a.x*b0.x; acc[j][1] += a.x*b0.y;
      acc[j][2] += a.x*b0.z; acc[j][3] += a.x*b0.w;
      acc[j][0] += a.y*b1.x; acc[j][1] += a.y*b1.y;
      acc[j][2] += a.y*b1.z; acc[j][3] += a.y*b1.w;
      acc[j][0] += a.z*b2.x; acc[j][1] += a.z*b2.y;
      acc[j][2] += a.z*b2.z; acc[j][3] += a.z*b2.w;
      acc[j][0] += a.w*b3.x; acc[j][1] += a.w*b3.y;
      acc[j][2] += a.w*b3.z; acc[j][3] += a.w*b3.w;
    }
  }
  // epilogue: bias + BN + ReLU, scatter-write raw rows, score = tanh(dot*invnorm)
  float invn = invn_p[0];
  float bi[4], scv[4], bt[4], mn[4], pwv[4];
  #pragma unroll
  for(int i=0;i<4;i++){
    int c = tx*4+i;
    bi[i]  = bias[c];
    scv[i] = gamma[c] * (1.0f/sqrtf(var[c] + BNEPS));
    bt[i]  = beta[c];
    mn[i]  = mean[c];
    pwv[i] = pw[c];
  }
  #pragma unroll
  for(int j=0;j<8;j++){
    int row = r0 + ty*8 + j;
    int orig = olist ? olist[row] : row;
    float v0 = fmaxf((acc[j][0]+bi[0]-mn[0])*scv[0]+bt[0], 0.f);
    float v1 = fmaxf((acc[j][1]+bi[1]-mn[1])*scv[1]+bt[1], 0.f);
    float v2 = fmaxf((acc[j][2]+bi[2]-mn[2])*scv[2]+bt[2], 0.f);
    float v3 = fmaxf((acc[j][3]+bi[3]-mn[3])*scv[3]+bt[3], 0.f);
    float4 o; o.x=v0; o.y=v1; o.z=v2; o.w=v3;
    *(float4*)(hout + (size_t)orig*HDIM + tx*4) = o;
    float p = v0*pwv[0]+v1*pwv[1]+v2*pwv[2]+v3*pwv[3];
    #pragma unroll
    for(int m=16;m>=1;m>>=1) p += __shfl_xor(p, m, 64);
    if(tx==0) score[row] = tanhf(p * invn);
  }
}

// ---------------- per-graph top-k: bitonic sort (score desc, idx asc) ----------------
__global__ __launch_bounds__(512) void k_topk(int n, int k, int P,
    const float* __restrict__ score, const int* __restrict__ curlist,
    float* __restrict__ vals, int* __restrict__ nextlist,
    float* __restrict__ dinvz, float* __restrict__ gsc){
  int g = blockIdx.x, t = threadIdx.x;
  __shared__ float s[1024];
  __shared__ int  id[1024];
  for(int i=t;i<P;i+=512){
    s[i]  = (i<n) ? score[g*n+i] : -FLT_MAX;
    id[i] = i;
  }
  __syncthreads();
  for(int k2=2;k2<=P;k2<<=1){
    for(int j=k2>>1;j>0;j>>=1){
      for(int i=t;i<P;i+=512){
        int ixj = i ^ j;
        if(ixj > i){
          bool desc = ((i & k2) == 0);
          float si = s[i], sx = s[ixj];
          int ii = id[i], ix = id[ixj];
          bool pre = (si > sx) || (si == sx && ii < ix);  // i precedes in desc order
          if(desc ? !pre : pre){ s[i]=sx; s[ixj]=si; id[i]=ix; id[ixj]=ii; }
        }
      }
      __syncthreads();
    }
  }
  for(int i=t;i<n;i+=512){
    int idx = id[i];
    int orig = curlist ? curlist[g*n+idx] : (g*NPG0 + idx);
    if(i<k){
      vals[g*k+i]=s[i]; nextlist[g*k+i]=orig;
    } else {
      dinvz[orig] = 0.f;               // node dies (alive sets nest)
      gsc[orig]   = 0.f;
    }
  }
}

// ---------------- pool partials + next-layer degree + gsc ----------------
__global__ __launch_bounds__(256) void k_gpd(int k, int do_deg,
    const float* __restrict__ hraw, const float* __restrict__ vals,
    const int* __restrict__ nextlist,
    float* __restrict__ sumst, float* __restrict__ maxst,
    const int* __restrict__ rp, const long long* __restrict__ ec,
    float* __restrict__ dinvz, float* __restrict__ gsc){
  int g = blockIdx.x & 63;
  int chunk = blockIdx.x >> 6;               // 0..POOL_NB-1
  int wid = threadIdx.x >> 6, lane = threadIdx.x & 63;
  int ww = chunk*4 + wid;                    // wave id within graph: 0..POOL_NB*4-1
  const int half = lane >> 5, sl32 = lane & 31;
  const int qw   = lane >> 4, sl16 = lane & 15;
  const int NH = POOL_NB*4*2;                // half-waves per graph
  float4 psum; psum.x=0.f; psum.y=0.f; psum.z=0.f; psum.w=0.f;
  float4 pmax; pmax.x=-FLT_MAX; pmax.y=-FLT_MAX; pmax.z=-FLT_MAX; pmax.w=-FLT_MAX;
  for(int j = ww*2 + half; j < k; j += NH){
    float v = vals[g*k+j];
    int d = nextlist[g*k+j];
    float4 hv = *(const float4*)(hraw + (size_t)d*HDIM + 4*sl32);
    float4 o; o.x=hv.x*v; o.y=hv.y*v; o.z=hv.z*v; o.w=hv.w*v;
    psum.x+=o.x; psum.y+=o.y; psum.z+=o.z; psum.w+=o.w;
    pmax.x=fmaxf(pmax.x,o.x); pmax.y=fmaxf(pmax.y,o.y);
    pmax.z=fmaxf(pmax.z,o.z); pmax.w=fmaxf(pmax.w,o.w);
  }
  if(do_deg){
    const int NQ = POOL_NB*4*4;              // quarter-waves per graph
    for(int j = ww*4 + qw; j < k; j += NQ){
      int d  = nextlist[g*k + j];
      int ld = d - g*NPG0;
      int e0 = rp[g*RPS+ld], e1 = rp[g*RPS+ld+1];
      float deg = 0.f;
      for(int b=e0+sl16; b<e1; b+=16){
        long long rec = ec[(size_t)g*EG + b];
        int s = (int)(rec & 0xffffffffLL);
        float w = __int_as_float((int)(rec>>32));
        if(dinvz[s] != 0.f) deg += w;
      }
      #pragma unroll
      for(int o=8;o>0;o>>=1) deg += __shfl_xor(deg, o, 64);  // within 16-lane group
      if(sl16==0){
        float dv = 1.0f / sqrtf(deg + 1.0f);
        dinvz[d] = dv;
        gsc[d] = dv * vals[g*k+j];
      }
    }
  }
  // cross-half reduce (each half covered all 128 features for its row subset)
  psum.x += __shfl_xor(psum.x, 32, 64); psum.y += __shfl_xor(psum.y, 32, 64);
  psum.z += __shfl_xor(psum.z, 32, 64); psum.w += __shfl_xor(psum.w, 32, 64);
  pmax.x = fmaxf(pmax.x, __shfl_xor(pmax.x, 32, 64));
  pmax.y = fmaxf(pmax.y, __shfl_xor(pmax.y, 32, 64));
  pmax.z = fmaxf(pmax.z, __shfl_xor(pmax.z, 32, 64));
  pmax.w = fmaxf(pmax.w, __shfl_xor(pmax.w, 32, 64));
  __shared__ float ss[4][128];
  __shared__ float sm[4][128];
  if(half==0){
    *(float4*)&ss[wid][4*sl32] = psum;
    *(float4*)&sm[wid][4*sl32] = pmax;
  }
  __syncthreads();
  int t = threadIdx.x;
  if(t < 128){
    float s = (ss[0][t]+ss[1][t]) + (ss[2][t]+ss[3][t]);
    float m = fmaxf(fmaxf(sm[0][t], sm[1][t]), fmaxf(sm[2][t], sm[3][t]));
    sumst[(size_t)(chunk*NGR + g)*HDIM + t] = s;
    maxst[(size_t)(chunk*NGR + g)*HDIM + t] = m;
  }
}

// ---------------- MLP head (folds 6 layers x POOL_NB chunk partials) ----------------
__global__ __launch_bounds__(512) void k_head(const float* __restrict__ sumstage,
    const float* __restrict__ maxstage,
    const float* __restrict__ d1w, const float* __restrict__ d1b,
    const float* __restrict__ d2w, const float* __restrict__ d2b, float* __restrict__ out){
  const float kinv[6] = {1.f/800.f, 1.f/640.f, 1.f/512.f, 1.f/410.f, 1.f/328.f, 1.f/263.f};
  int g = blockIdx.x, j = threadIdx.x;
  __shared__ float fl[256];
  __shared__ float hd[512];
  if(j < 128){
    float s = 0.f;
    #pragma unroll
    for(int l=0;l<6;l++){
      float ls = 0.f;
      for(int c=0;c<POOL_NB;c++)
        ls += sumstage[(size_t)((l*POOL_NB + c)*NGR + g)*HDIM + j];
      s += ls * kinv[l];
    }
    fl[j] = s;
  } else if(j < 256){
    int f = j - 128;
    float m = 0.f;
    #pragma unroll
    for(int l=0;l<6;l++){
      float lm = -FLT_MAX;
      for(int c=0;c<POOL_NB;c++)
        lm = fmaxf(lm, maxstage[(size_t)((l*POOL_NB + c)*NGR + g)*HDIM + f]);
      m += lm;
    }
    fl[j] = m;
  }
  __syncthreads();
  float acc = d1b[j];
  for(int i=0;i<256;i++) acc += fl[i]*d1w[i*512+j];
  hd[j] = fmaxf(acc, 0.f);
  __syncthreads();
  if(j < 10){
    float a = d2b[j];
    for(int i=0;i<512;i++) a += hd[i]*d2w[i*10+j];
    out[g*10+j] = a;
  }
}

extern "C" void kernel_launch(void* const* d_in, const int* in_sizes, int n_in,
                              void* d_out, int out_size, void* d_ws, size_t ws_size,
                              hipStream_t stream) {
  const float* x    = (const float*)d_in[0];
  const int* ei     = (const int*)d_in[1];
  const float* ew   = (const float*)d_in[3];
  const float* conv1w = (const float*)d_in[4];
  const float* convw  = (const float*)d_in[5];
  const float* convb  = (const float*)d_in[6];
  const float* bng    = (const float*)d_in[7];
  const float* bnb    = (const float*)d_in[8];
  const float* bnm    = (const float*)d_in[9];
  const float* bnv    = (const float*)d_in[10];
  const float* poolw  = (const float*)d_in[11];
  const float* d1w    = (const float*)d_in[12];
  const float* d1b    = (const float*)d_in[13];
  const float* d2w    = (const float*)d_in[14];
  const float* d2b    = (const float*)d_in[15];
  float* out = (float*)d_out;

  char* w = (char*)d_ws;
  float* horig = (float*)w; w += (size_t)64000*128*4;   // raw gemm outputs by ORIGINAL node id
  float* hc    = (float*)w; w += (size_t)64000*128*4;   // agg output compact (gemm A input)
  float* agg0  = (float*)w; w += (size_t)64000*64*4;    // layer-0 aggregation (64 cols)
  long long* ec = (long long*)w; w += (size_t)NE*8;     // static (w, src_orig), dst-bucketed
  int*   rp    = (int*)w;   w += (size_t)NGR*RPS*4;
  int*   pcnt  = (int*)w;   w += (size_t)256*NPG0*4;
  float* pdeg  = (float*)w; w += (size_t)256*NPG0*4;
  float* dinvz = (float*)w; w += (size_t)64000*4;       // 0 == node dead (alive indicator)
  float* gsc   = (float*)w; w += (size_t)64000*4;       // dinv_new * topk_val (0 == dead)
  float* score = (float*)w; w += (size_t)64000*4;
  float* vals  = (float*)w; w += (size_t)51200*4;
  int*   listA = (int*)w;   w += (size_t)51200*4;
  int*   listB = (int*)w;   w += (size_t)51200*4;
  float* invno = (float*)w; w += 64;
  float* sumstage = (float*)w; w += (size_t)6*POOL_NB*NGR*HDIM*4;
  float* maxstage = (float*)w; w += (size_t)6*POOL_NB*NGR*HDIM*4;

  k_invnorm<<<6,128,0,stream>>>(poolw, invno);

  const int ns[6]={1000,800,640,512,410,328};
  const int ks[6]={800,640,512,410,328,263};

  // ---- one-time CSR build (original ids): count partials, then fused scan+scatter ----
  k_count0<<<256,256,0,stream>>>(ei+NE, ew, pcnt, pdeg);
  k_build<<<64,1024,0,stream>>>(pcnt, pdeg, ei, ei+NE, ew, rp, dinvz, gsc, ec);

  // ---- layer 0 (input = x, 64 cols) ----
  k_agg<1><<<64*32,256,0,stream>>>(1000, nullptr, rp, ec, dinvz, gsc, x, agg0);
  k_gemm<64><<<1000,256,0,stream>>>(agg0, conv1w, convb, bng, bnb, bnm, bnv, poolw, invno,
                                    nullptr, horig, score);
  k_topk<<<64,512,0,stream>>>(1000, 800, 1024, score, nullptr, vals, listA, dinvz, gsc);
  k_gpd<<<64*POOL_NB,256,0,stream>>>(800, 1, horig, vals, listA,
                                     sumstage, maxstage, rp, ec, dinvz, gsc);

  // ---- layers 1..5 ----
  int* cur = listA; int* nxt = listB;
  for(int i=1;i<6;i++){
    int n = ns[i], k = ks[i];
    k_agg<0><<<64*32,256,0,stream>>>(n, cur, rp, ec, dinvz, gsc, horig, hc);
    k_gemm<128><<<n,256,0,stream>>>(hc, convw+(size_t)(i-1)*128*128, convb+i*128, bng+i*128,
                                    bnb+i*128, bnm+i*128, bnv+i*128, poolw+i*128, invno+i,
                                    cur, horig, score);
    int P = (n > 512) ? 1024 : 512;
    k_topk<<<64,512,0,stream>>>(n, k, P, score, cur, vals, nxt, dinvz, gsc);
    k_gpd<<<64*POOL_NB,256,0,stream>>>(k, (i<5)?1:0, horig, vals, nxt,
                                       sumstage + (size_t)i*POOL_NB*NGR*HDIM,
                                       maxstage + (size_t)i*POOL_NB*NGR*HDIM,
                                       rp, ec, dinvz, gsc);
    int* tmp = cur; cur = nxt; nxt = tmp;
  }

  k_head<<<64,512,0,stream>>>(sumstage, maxstage, d1w, d1b, d2w, d2b, out);
}